// Round 10
// baseline (130.566 us; speedup 1.0000x reference)
//
#include <hip/hip_runtime.h>
#include <hip/hip_bf16.h>
#include <math.h>

// CasperNet R10: B=131072, D=256, H=64, O=10.
// vs R9 (63.5us, real VALUBusy ~58%, occ 43%, serial bpermute chain):
//  - QUAD-STEP cascade: 16 rounds x 4 neurons. Batch-broadcast the 4 cols'
//    pre-activations (16 bpermutes, one latency), then triangular in-quad
//    fixup in f32: h1=sig(s1+c10 h0), h2=sig(s2+c20 h0+c21 h1),
//    h3=sig(s3+c30 h0+c31 h1+c32 h2). Serial path 64x~70cy -> 16x~110cy.
//    Within-quad acc entries go stale after their h is fixed -- they are
//    never read again, so the rank-1 updates stay consistent.
//  - LDS 62->54.1KB (U as bf16x4, head packed f32x4/quad): 3 blocks/CU
//    (24 waves, 75%) if VGPR<=85. Keep (512,2) so a fat allocation
//    degrades to 2 blocks instead of spilling (R6-R8 lesson).
//  - x->bf16 via __float2bfloat16 (compiler cvt; was 3-instr manual RNE).
// Layout (verified R5): MFMA C: col=lane&15, row=(lane>>4)*4+reg.

#define DIMD 256
#define DIMH 64
#define DIMO 10
#define DT   320
#define NT   5        // 5 n-tiles of 16 = 80 cols (74 used)
#define TM   128      // rows per block: 8 waves x 16
#define BLOCK 512

typedef __attribute__((ext_vector_type(4))) float f32x4;
typedef __attribute__((ext_vector_type(8))) short bf16x8;

__device__ inline unsigned short f2bf(float f) {   // staging-only (RNE)
    union { float f; unsigned u; } v; v.f = f;
    unsigned r = v.u + 0x7FFFu + ((v.u >> 16) & 1u);
    return (unsigned short)(r >> 16);
}
__device__ inline short f2bf_fast(float f) {       // hot path: compiler cvt
    __hip_bfloat16 h = __float2bfloat16(f);
    return __builtin_bit_cast(short, h);
}
__device__ inline float bf2f(unsigned short u) {
    union { unsigned u; float f; } v; v.u = ((unsigned)u) << 16; return v.f;
}
__device__ inline float sigm(float s) {
    return __builtin_amdgcn_rcpf(1.0f + __expf(-s));   // v_rcp_f32
}

__global__ __launch_bounds__(BLOCK, 2) void caspernet_kernel(
    const float* __restrict__ x,    // [B, 256]
    const float* __restrict__ Wh,   // [64, 320]
    const float* __restrict__ bh,   // [64]
    const float* __restrict__ Wo,   // [10, 320]
    const float* __restrict__ bo,   // [10]
    float* __restrict__ out,        // [B, 10]
    int B)
{
    __shared__ short   sW[80 * DIMD];    // bf16 [n][k] swizzled       40960B
    __shared__ ushort4 sU4b[DIMH * 16];  // [i][c]: bf16 U, cols c+16t  8192B
    __shared__ f32x4   sWoh4[16 * 16];   // [quad][c]: head w, 4 cols   4096B
    __shared__ float   sQC[16 * 8];      // [quad][6]: in-quad coeffs    512B
    __shared__ float   sBias[80];        //                              320B
                                         // total ~54.1KB -> 3 blocks/CU

    const int tid = threadIdx.x;

    // ---- stage W1 = [Wh_x; Wo_x] as bf16, swizzled ----
    for (int idx = tid; idx < 80 * 64; idx += BLOCK) {   // 80 rows x 64 float4
        const int n = idx >> 6, k0 = (idx & 63) * 4;
        float4 v = make_float4(0.f, 0.f, 0.f, 0.f);
        if (n < DIMH)      v = *reinterpret_cast<const float4*>(Wh + n * DT + k0);
        else if (n < 74)   v = *reinterpret_cast<const float4*>(Wo + (n - 64) * DT + k0);
        const int kz = k0 ^ ((n & 7) << 3);
        short* d = sW + n * DIMD + kz;
        d[0] = (short)f2bf(v.x); d[1] = (short)f2bf(v.y);
        d[2] = (short)f2bf(v.z); d[3] = (short)f2bf(v.w);
    }
    // ---- cascade U weights, pre-masked, bf16 ----
    for (int idx = tid; idx < DIMH * 16; idx += BLOCK) {
        const int i = idx >> 4, c = idx & 15;
        ushort4 u;
        u.x = (c      > i) ? f2bf(Wh[(c     ) * DT + DIMD + i]) : (unsigned short)0;
        u.y = (16 + c > i) ? f2bf(Wh[(16 + c) * DT + DIMD + i]) : (unsigned short)0;
        u.z = (32 + c > i) ? f2bf(Wh[(32 + c) * DT + DIMD + i]) : (unsigned short)0;
        u.w = (48 + c > i) ? f2bf(Wh[(48 + c) * DT + DIMD + i]) : (unsigned short)0;
        sU4b[idx] = u;
    }
    // ---- head weights packed per quad ----
    for (int idx = tid; idx < 16 * 16; idx += BLOCK) {
        const int qd = idx >> 4, c = idx & 15;
        f32x4 v;
        #pragma unroll
        for (int q = 0; q < 4; ++q)
            v[q] = (c < DIMO) ? Wo[c * DT + DIMD + (qd * 4 + q)] : 0.f;
        sWoh4[idx] = v;
    }
    // ---- in-quad coefficients c[q][m] = U[i0+q][i0+m] (f32, exact path) ----
    if (tid < 96) {
        const int qd = tid / 6, k = tid % 6;
        const int q = (k == 0) ? 1 : (k < 3) ? 2 : 3;
        const int m = (k == 0) ? 0 : (k < 3) ? (k - 1) : (k - 3);
        sQC[qd * 8 + k] = Wh[(qd * 4 + q) * DT + DIMD + (qd * 4 + m)];
    }
    if (tid < 80) sBias[tid] = (tid < 64) ? bh[tid] : ((tid < 74) ? bo[tid - 64] : 0.f);
    __syncthreads();

    const int l  = tid & 63;
    const int w  = tid >> 6;            // wave 0..7 -> rows w*16..w*16+15
    const int lm = l & 15, lg = l >> 4;

    // ---- phase 1: one 16-row tile per wave ----
    const size_t rowA = (size_t)blockIdx.x * TM + w * 16 + lm;
    const float* xr = x + rowA * DIMD + lg * 8;

    f32x4 acc[NT];
    #pragma unroll
    for (int t = 0; t < NT; ++t) acc[t] = (f32x4){0.f, 0.f, 0.f, 0.f};

    #pragma unroll
    for (int ks = 0; ks < 8; ++ks) {
        const float4 xa = *reinterpret_cast<const float4*>(xr + ks * 32);
        const float4 xb = *reinterpret_cast<const float4*>(xr + ks * 32 + 4);
        bf16x8 af;
        af[0] = f2bf_fast(xa.x); af[1] = f2bf_fast(xa.y);
        af[2] = f2bf_fast(xa.z); af[3] = f2bf_fast(xa.w);
        af[4] = f2bf_fast(xb.x); af[5] = f2bf_fast(xb.y);
        af[6] = f2bf_fast(xb.z); af[7] = f2bf_fast(xb.w);
        #pragma unroll
        for (int t = 0; t < NT; ++t) {
            const int n = t * 16 + lm;
            const int kz = (lg * 8 + ks * 32) ^ ((n & 7) << 3);
            const bf16x8 bf = *reinterpret_cast<const bf16x8*>(sW + n * DIMD + kz);
            acc[t] = __builtin_amdgcn_mfma_f32_16x16x32_bf16(af, bf, acc[t], 0, 0, 0);
        }
    }
    #pragma unroll
    for (int t = 0; t < NT; ++t) {
        const float bt = sBias[t * 16 + lm];
        acc[t][0] += bt; acc[t][1] += bt; acc[t][2] += bt; acc[t][3] += bt;
    }

    // ---- phase 2: quad-step cascade (16 rounds x 4 neurons) ----
    const int gbase = l & 48;
    #pragma unroll
    for (int rq = 0; rq < 16; ++rq) {
        const int i0 = rq * 4;
        const int ti = i0 >> 4, ci = i0 & 15;    // all 4 cols in one tile
        // batch-broadcast pre-activations for cols i0..i0+3, rows 0..3
        float s[4][4];
        #pragma unroll
        for (int q = 0; q < 4; ++q)
            #pragma unroll
            for (int rr = 0; rr < 4; ++rr)
                s[q][rr] = __shfl(acc[ti][rr], gbase | (ci + q), 64);
        const f32x4 qa = *reinterpret_cast<const f32x4*>(&sQC[rq * 8]);     // c10,c20,c21,c30
        const float2 qb = *reinterpret_cast<const float2*>(&sQC[rq * 8 + 4]); // c31,c32
        // triangular in-quad fixup (VALU-only serial chain)
        float h[4][4];
        #pragma unroll
        for (int rr = 0; rr < 4; ++rr) {
            const float h0 = sigm(s[0][rr]);
            const float h1 = sigm(fmaf(qa[0], h0, s[1][rr]));
            const float h2 = sigm(fmaf(qa[2], h1, fmaf(qa[1], h0, s[2][rr])));
            const float h3 = sigm(fmaf(qb.y, h2, fmaf(qb.x, h1,
                                  fmaf(qa[3], h0, s[3][rr]))));
            h[0][rr] = h0; h[1][rr] = h1; h[2][rr] = h2; h[3][rr] = h3;
        }
        // rank-1 updates for all 4 neurons (masked weights: cols<=i are 0)
        const f32x4 wo4 = sWoh4[rq * 16 + lm];
        #pragma unroll
        for (int q = 0; q < 4; ++q) {
            const ushort4 ub = sU4b[(i0 + q) * 16 + lm];
            const float uu[4] = { bf2f(ub.x), bf2f(ub.y), bf2f(ub.z), bf2f(ub.w) };
            #pragma unroll
            for (int t = ti; t < 4; ++t) {
                acc[t][0] = fmaf(uu[t], h[q][0], acc[t][0]);
                acc[t][1] = fmaf(uu[t], h[q][1], acc[t][1]);
                acc[t][2] = fmaf(uu[t], h[q][2], acc[t][2]);
                acc[t][3] = fmaf(uu[t], h[q][3], acc[t][3]);
            }
            const float wo = wo4[q];
            acc[4][0] = fmaf(wo, h[q][0], acc[4][0]);
            acc[4][1] = fmaf(wo, h[q][1], acc[4][1]);
            acc[4][2] = fmaf(wo, h[q][2], acc[4][2]);
            acc[4][3] = fmaf(wo, h[q][3], acc[4][3]);
        }
    }

    // ---- store head tile (cols 64..73 = C-tile 4) ----
    if (lm < DIMO) {
        const size_t orow0 = (size_t)blockIdx.x * TM + w * 16 + lg * 4;
        #pragma unroll
        for (int r = 0; r < 4; ++r)
            out[(orow0 + r) * DIMO + lm] = acc[4][r];
    }
}

extern "C" void kernel_launch(void* const* d_in, const int* in_sizes, int n_in,
                              void* d_out, int out_size, void* d_ws, size_t ws_size,
                              hipStream_t stream) {
    const float* x  = (const float*)d_in[0];
    const float* Wh = (const float*)d_in[1];
    const float* bh = (const float*)d_in[2];
    const float* Wo = (const float*)d_in[3];
    const float* bo = (const float*)d_in[4];
    float* out = (float*)d_out;

    const int B = in_sizes[0] / DIMD;      // 131072
    const int grid = B / TM;               // 1024

    hipLaunchKernelGGL(caspernet_kernel, dim3(grid), dim3(BLOCK), 0, stream,
                       x, Wh, bh, Wo, bo, out, B);
}

// Round 12
// 64.525 us; speedup vs baseline: 2.0235x; 2.0235x over previous
//
#include <hip/hip_runtime.h>
#include <math.h>

// CasperNet R12: B=131072, D=256, H=64, O=10.
// R11 failed the POST-TIMING revalidation (first check passed) -- no
// code-level determinism bug found; reverting its two numeric deltas
// (bf16 U, __float2bfloat16) back to R9's known-passing numerics.
// Perf change vs R9 (63.5us, 16 waves/CU, 2 sequential block-rounds):
//   BLOCK=1024 (16 waves), TM=256, grid=512: LDS 61.7KB -> 2 blocks/CU
//   -> 32 waves/CU (8/SIMD, 100% nominal occupancy), grid = exactly
//   2 x 256 CUs -> no tail round.
// VGPR: (1024,2) caps at 131072/2048 = 64; R9's measured usage is 52 ->
// fits without spill (R2-R4 died at this cap because they needed ~100).
// Layout (verified R5): MFMA C: col=lane&15, row=(lane>>4)*4+reg; cascade
// runs directly on C-frags; sigmoid via v_rcp_f32.

#define DIMD 256
#define DIMH 64
#define DIMO 10
#define DT   320
#define NT   5        // 5 n-tiles of 16 = 80 cols (74 used)
#define TM   256      // rows per block: 16 waves x 16
#define BLOCK 1024

typedef __attribute__((ext_vector_type(4))) float f32x4;
typedef __attribute__((ext_vector_type(8))) short bf16x8;

__device__ inline unsigned short f2bf(float f) {   // RNE, deterministic
    union { float f; unsigned u; } v; v.f = f;
    unsigned r = v.u + 0x7FFFu + ((v.u >> 16) & 1u);
    return (unsigned short)(r >> 16);
}
__device__ inline float sigm(float s) {
    return __builtin_amdgcn_rcpf(1.0f + __expf(-s));   // v_rcp_f32
}

__global__ __launch_bounds__(BLOCK, 2) void caspernet_kernel(
    const float* __restrict__ x,    // [B, 256]
    const float* __restrict__ Wh,   // [64, 320]
    const float* __restrict__ bh,   // [64]
    const float* __restrict__ Wo,   // [10, 320]
    const float* __restrict__ bo,   // [10]
    float* __restrict__ out,        // [B, 10]
    int B)
{
    __shared__ short sW[80 * DIMD];     // bf16 [n][k], k XOR-swizzled; 40KB
    __shared__ f32x4 sU4[DIMH * 16];    // [i][c]: U for cols c+16t;     16KB
    __shared__ float sWoh[DIMH * 16];   // [i][c]: head col c (0 pad);    4KB
    __shared__ float sBias[80];         //                               320B
                                        // total 61.7KB -> 2 blocks/CU

    const int tid = threadIdx.x;

    // ---- stage W1 = [Wh_x; Wo_x] as bf16, swizzled ----
    for (int idx = tid; idx < 80 * 64; idx += BLOCK) {   // 80 rows x 64 float4
        const int n = idx >> 6, k0 = (idx & 63) * 4;
        float4 v = make_float4(0.f, 0.f, 0.f, 0.f);
        if (n < DIMH)      v = *reinterpret_cast<const float4*>(Wh + n * DT + k0);
        else if (n < 74)   v = *reinterpret_cast<const float4*>(Wo + (n - 64) * DT + k0);
        const int kz = k0 ^ ((n & 7) << 3);
        short* d = sW + n * DIMD + kz;
        d[0] = (short)f2bf(v.x); d[1] = (short)f2bf(v.y);
        d[2] = (short)f2bf(v.z); d[3] = (short)f2bf(v.w);
    }
    // ---- cascade weights (pre-masked, f32) + head + bias ----
    for (int idx = tid; idx < DIMH * 16; idx += BLOCK) {
        const int i = idx >> 4, c = idx & 15;
        f32x4 u;
        u[0] = (c      > i) ? Wh[(c     ) * DT + DIMD + i] : 0.f;
        u[1] = (16 + c > i) ? Wh[(16 + c) * DT + DIMD + i] : 0.f;
        u[2] = (32 + c > i) ? Wh[(32 + c) * DT + DIMD + i] : 0.f;
        u[3] = (48 + c > i) ? Wh[(48 + c) * DT + DIMD + i] : 0.f;
        sU4[idx] = u;
        sWoh[idx] = (c < DIMO) ? Wo[c * DT + DIMD + i] : 0.f;
    }
    if (tid < 80) sBias[tid] = (tid < 64) ? bh[tid] : ((tid < 74) ? bo[tid - 64] : 0.f);
    __syncthreads();

    const int l  = tid & 63;
    const int w  = tid >> 6;            // wave 0..15 -> rows w*16..w*16+15
    const int lm = l & 15, lg = l >> 4;

    // ---- phase 1: one 16-row tile per wave ----
    const size_t rowA = (size_t)blockIdx.x * TM + w * 16 + lm;
    const float* xr = x + rowA * DIMD + lg * 8;

    f32x4 acc[NT];
    #pragma unroll
    for (int t = 0; t < NT; ++t) acc[t] = (f32x4){0.f, 0.f, 0.f, 0.f};

    #pragma unroll
    for (int ks = 0; ks < 8; ++ks) {
        const float4 xa = *reinterpret_cast<const float4*>(xr + ks * 32);
        const float4 xb = *reinterpret_cast<const float4*>(xr + ks * 32 + 4);
        bf16x8 af;
        af[0] = (short)f2bf(xa.x); af[1] = (short)f2bf(xa.y);
        af[2] = (short)f2bf(xa.z); af[3] = (short)f2bf(xa.w);
        af[4] = (short)f2bf(xb.x); af[5] = (short)f2bf(xb.y);
        af[6] = (short)f2bf(xb.z); af[7] = (short)f2bf(xb.w);
        #pragma unroll
        for (int t = 0; t < NT; ++t) {
            const int n = t * 16 + lm;
            const int kz = (lg * 8 + ks * 32) ^ ((n & 7) << 3);
            const bf16x8 bf = *reinterpret_cast<const bf16x8*>(sW + n * DIMD + kz);
            acc[t] = __builtin_amdgcn_mfma_f32_16x16x32_bf16(af, bf, acc[t], 0, 0, 0);
        }
    }
    #pragma unroll
    for (int t = 0; t < NT; ++t) {
        const float bt = sBias[t * 16 + lm];
        acc[t][0] += bt; acc[t][1] += bt; acc[t][2] += bt; acc[t][3] += bt;
    }

    // ---- phase 2: cascade on the C-layout (R9 structure, unchanged) ----
    const int gbase = l & 48;
    #pragma unroll
    for (int i = 0; i < DIMH; ++i) {
        const int ti = i >> 4, ci = i & 15;
        const float s0 = __shfl(acc[ti][0], gbase | ci, 64);
        const float s1 = __shfl(acc[ti][1], gbase | ci, 64);
        const float s2 = __shfl(acc[ti][2], gbase | ci, 64);
        const float s3 = __shfl(acc[ti][3], gbase | ci, 64);
        const float h0 = sigm(s0), h1 = sigm(s1);
        const float h2 = sigm(s2), h3 = sigm(s3);
        const f32x4 uv = sU4[i * 16 + lm];
        const float wo = sWoh[i * 16 + lm];
        #pragma unroll
        for (int t = ti; t < 4; ++t) {          // cols <= i carry zero weights
            acc[t][0] = fmaf(uv[t], h0, acc[t][0]);
            acc[t][1] = fmaf(uv[t], h1, acc[t][1]);
            acc[t][2] = fmaf(uv[t], h2, acc[t][2]);
            acc[t][3] = fmaf(uv[t], h3, acc[t][3]);
        }
        acc[4][0] = fmaf(wo, h0, acc[4][0]);
        acc[4][1] = fmaf(wo, h1, acc[4][1]);
        acc[4][2] = fmaf(wo, h2, acc[4][2]);
        acc[4][3] = fmaf(wo, h3, acc[4][3]);
    }

    // ---- store head tile (cols 64..73 = C-tile 4) ----
    if (lm < DIMO) {
        const size_t orow0 = (size_t)blockIdx.x * TM + w * 16 + lg * 4;
        #pragma unroll
        for (int r = 0; r < 4; ++r)
            out[(orow0 + r) * DIMO + lm] = acc[4][r];
    }
}

extern "C" void kernel_launch(void* const* d_in, const int* in_sizes, int n_in,
                              void* d_out, int out_size, void* d_ws, size_t ws_size,
                              hipStream_t stream) {
    const float* x  = (const float*)d_in[0];
    const float* Wh = (const float*)d_in[1];
    const float* bh = (const float*)d_in[2];
    const float* Wo = (const float*)d_in[3];
    const float* bo = (const float*)d_in[4];
    float* out = (float*)d_out;

    const int B = in_sizes[0] / DIMD;      // 131072
    const int grid = B / TM;               // 512 = 2 blocks/CU x 256 CUs

    hipLaunchKernelGGL(caspernet_kernel, dim3(grid), dim3(BLOCK), 0, stream,
                       x, Wh, bh, Wo, bo, out, B);
}